// Round 1
// 225.396 us; speedup vs baseline: 1.0289x; 1.0289x over previous
//
#include <hip/hip_runtime.h>

#define NB 32
#define NP 512
#define NS 1024
#define NH 1024
#define NR 256
#define K3 3072

#define BM 64
#define BK 64

typedef short short8 __attribute__((ext_vector_type(8)));
typedef short short4v __attribute__((ext_vector_type(4)));
typedef __bf16 bf16x8 __attribute__((ext_vector_type(8)));
typedef float f32x4 __attribute__((ext_vector_type(4)));

__device__ __forceinline__ unsigned short f2bf(float f) {
  unsigned u = __builtin_bit_cast(unsigned, f);
  u += 0x7fffu + ((u >> 16) & 1u);   // round-to-nearest-even
  return (unsigned short)(u >> 16);
}

__device__ __forceinline__ f32x4 mfma_bf16(short8 a, short8 b, f32x4 c) {
  return __builtin_amdgcn_mfma_f32_16x16x32_bf16(
      __builtin_bit_cast(bf16x8, a), __builtin_bit_cast(bf16x8, b), c, 0, 0, 0);
}

// W fp32 [256][3072] -> FRAGMENT-MAJOR bf16 in ws:
//   WbF[kc][n16][lane] (short8), kc = k3/32 (96), n16 = n/16 (16), lane = lr+16*lg.
//   A wave's B-fragment load is one contiguous 1 KB burst (16 lines).
__global__ void wconv_kernel(const float* __restrict__ W,
                             unsigned short* __restrict__ WbF) {
  int i = blockIdx.x * blockDim.x + threadIdx.x;   // short8 id, 98304 total
  int lane = i & 63, n16 = (i >> 6) & 15, kc = i >> 10;
  int lr = lane & 15, lg = lane >> 4;
  const float* src = W + (size_t)(n16 * 16 + lr) * K3 + kc * 32 + lg * 8;
  float4 a = *(const float4*)src;
  float4 b = *(const float4*)(src + 4);
  short8 o;
  o[0] = (short)f2bf(a.x); o[1] = (short)f2bf(a.y);
  o[2] = (short)f2bf(a.z); o[3] = (short)f2bf(a.w);
  o[4] = (short)f2bf(b.x); o[5] = (short)f2bf(b.y);
  o[6] = (short)f2bf(b.z); o[7] = (short)f2bf(b.w);
  *(short8*)(WbF + (size_t)i * 8) = o;
}

// Fused gather + 3-part bf16 MFMA GEMM.
// R6 restructure: grid was 256 blocks x 8 waves = 1 block/CU = 25% occupancy
// (measured 21.5%, MfmaUtil 12%) -> latency-bound on the per-stage barrier
// behind random-latency gathers. Now 1024 threads (16 waves, wave = 16 N-cols)
// for 50% occupancy at unchanged W/L2 traffic, and the gather register
// prefetch is 2 STAGES deep (ldA/ldB ping-pong): the vmcnt wait at
// store_stage has ~2 compute stages + a barrier of slack (>1000 cyc), which
// covers worst-case L3/HBM gather latency. W fragments stay register-
// prefetched one stage ahead and are issued BEFORE the gathers each stage so
// no MFMA waits on the ordered vmcnt queue behind a gather.
__global__ __launch_bounds__(1024, 4) void gemm_kernel(
    const int* __restrict__ pairs, const float* __restrict__ hs,
    const unsigned short* __restrict__ WbF, const float* __restrict__ bias,
    float* __restrict__ out) {
  __shared__ __align__(16) unsigned short sA[2][3][BM][64];  // 49152 B

  const int tid = threadIdx.x;
  const int blk = blockIdx.x;
  // XCD swizzle: blockIdx round-robins over 8 XCDs; give XCD x batches
  // 4x..4x+3 so a batch's 8 M-tiles share one XCD's L2 (R5: FETCH 122->63 MB).
  const int x     = blk & 7;
  const int jb    = blk >> 3;
  const int batch = x * 4 + (jb >> 3);
  const int mtile = jb & 7;
  const int m0    = (batch * 8 + mtile) * BM;

  // gather: 16 threads per pair; thread q covers float-cols {4q..4q+3} of each
  // of the 4 source rows (4 x float4 per stage per thread)
  const int pairi = tid >> 4;
  const int q     = tid & 15;
  int4 pr = ((const int4*)pairs)[m0 + pairi];
  const float* hb = hs + (size_t)batch * NS * NH;
  const float* rp[4];
  rp[0] = hb + (size_t)pr.x * NH + 4 * q;   // h_start
  rp[1] = hb + (size_t)pr.y * NH + 4 * q;   // h_end
  rp[2] = hb + (size_t)pr.z * NH + 4 * q;   // t_start
  rp[3] = hb + (size_t)pr.w * NH + 4 * q;   // t_end

  // MFMA lane mapping: 16 waves, wave w owns N-cols w*16..w*16+15
  const int lane = tid & 63;
  const int w    = tid >> 6;           // wave 0..15
  const int lr   = lane & 15;
  const int lg   = lane >> 4;

  // frag-major W: short addr = kc*8192 + n16*512 + lane*8; this wave: n16=w
  const unsigned short* wbase = WbF + (size_t)w * 512 + (size_t)lane * 8;

  f32x4 acc[4];
#pragma unroll
  for (int i = 0; i < 4; ++i) acc[i] = (f32x4){0.f, 0.f, 0.f, 0.f};

  float4 ldA[4], ldB[4];        // gather prefetch, TWO stages deep (ping-pong)
  short8 wcur[6], wnxt[6];      // W frags: idx = part*2 + ks

  auto load_w = [&](int s, short8* wd) {
#pragma unroll
    for (int part = 0; part < 3; ++part)
#pragma unroll
      for (int ks = 0; ks < 2; ++ks)
        wd[part * 2 + ks] = *(const short8*)(
            wbase + (size_t)(part * 32 + s * 2 + ks) * 8192);
  };

  auto load_gather = [&](int s, float4* ld) {
#pragma unroll
    for (int r = 0; r < 4; ++r)
      ld[r] = *(const float4*)(rp[r] + s * BK);
  };

  auto store_stage = [&](int buf, float4* ld) {
    short4v hv, tv, pv;
#pragma unroll
    for (int e = 0; e < 4; ++e) {
      float h = 0.5f * (((const float*)&ld[0])[e] + ((const float*)&ld[1])[e]);
      float t = 0.5f * (((const float*)&ld[2])[e] + ((const float*)&ld[3])[e]);
      float p = h * t;                 // product in fp32, rounded once
      hv[e] = (short)f2bf(h); tv[e] = (short)f2bf(t); pv[e] = (short)f2bf(p);
    }
    const int chunkI = q >> 1;
    const int col = ((chunkI ^ (pairi & 7)) * 8) + (q & 1) * 4;  // XOR swizzle
    *(short4v*)&sA[buf][0][pairi][col] = hv;
    *(short4v*)&sA[buf][1][pairi][col] = tv;
    *(short4v*)&sA[buf][2][pairi][col] = pv;
  };

  auto compute = [&](int buf, short8* wc) {
#pragma unroll
    for (int ks = 0; ks < 2; ++ks) {
      short8 ah[4], at4[4], ap[4];
      const int col = (((ks * 4 + lg) ^ (lr & 7)) * 8);          // XOR swizzle
#pragma unroll
      for (int i = 0; i < 4; ++i) {
        ah[i]  = *(const short8*)&sA[buf][0][i * 16 + lr][col];
        at4[i] = *(const short8*)&sA[buf][1][i * 16 + lr][col];
        ap[i]  = *(const short8*)&sA[buf][2][i * 16 + lr][col];
      }
#pragma unroll
      for (int i = 0; i < 4; ++i) {
        acc[i] = mfma_bf16(ah[i],  wc[0 + ks], acc[i]);
        acc[i] = mfma_bf16(at4[i], wc[2 + ks], acc[i]);
        acc[i] = mfma_bf16(ap[i],  wc[4 + ks], acc[i]);
      }
    }
  };

  // prologue: gather(0) -> LDS buf 0, W(0) -> wcur, gather(1) -> ldA
  load_gather(0, ldA);
  load_w(0, wcur);
  store_stage(0, ldA);          // waits only the 4 gather(0) loads
  load_gather(1, ldA);          // data for stage 0's store (consumed there)

  // stage s: consumes wc=W(s) [issued s-1] and ldc=gather(s+1) [issued s-1];
  // issues W(s+1) FIRST in the vmem queue, then gather(s+2) into ldn.
  auto stage = [&](int s, short8* wc, short8* wn, float4* ldc, float4* ldn) {
    __syncthreads();                     // buf[s&1] + wc ready
    if (s < 15) load_w(s + 1, wn);       // W FIRST in the vmem queue
    if (s < 14) load_gather(s + 2, ldn); // slow gathers AFTER, 2 stages ahead
    compute(s & 1, wc);                  // registers + LDS only
    if (s < 15) store_stage((s & 1) ^ 1, ldc);  // ~2 stages of vmcnt slack
  };

#pragma unroll 1
  for (int sp = 0; sp < 8; ++sp) {       // ping-pong W and gather reg buffers
    stage(2 * sp,     wcur, wnxt, ldA, ldB);
    stage(2 * sp + 1, wnxt, wcur, ldB, ldA);
  }

  // Epilogue: C/D layout row=(lane>>4)*4+reg, col=lane&15
  const int col  = w * 16 + lr;
  const float bv = bias[col];
#pragma unroll
  for (int i = 0; i < 4; ++i) {
    const size_t rbase = (size_t)(m0 + i * 16 + lg * 4) * NR + col;
#pragma unroll
    for (int r = 0; r < 4; ++r)
      out[rbase + (size_t)r * NR] = acc[i][r] + bv;
  }
}

extern "C" void kernel_launch(void* const* d_in, const int* in_sizes, int n_in,
                              void* d_out, int out_size, void* d_ws, size_t ws_size,
                              hipStream_t stream) {
  const int*   pairs = (const int*)d_in[0];
  const float* hs    = (const float*)d_in[1];
  const float* W     = (const float*)d_in[2];
  const float* bias  = (const float*)d_in[3];
  float* out = (float*)d_out;
  unsigned short* WbF = (unsigned short*)d_ws;   // 1.5 MB frag-major bf16 W

  wconv_kernel<<<(96 * 16 * 64) / 256, 256, 0, stream>>>(W, WbF);
  gemm_kernel<<<(NB * NP) / BM, 1024, 0, stream>>>(pairs, hs, WbF, bias, out);
}